// Round 6
// baseline (955.948 us; speedup 1.0000x reference)
//
#include <hip/hip_runtime.h>
#include <math.h>

#define BB 8
#define NPTS 80000
#define KK 5
#define FF 20
#define GG 125                 // blocks per batch -> 1000 blocks, 10 tiles each
#define TILE 64
#define NTILES (NPTS / TILE)   // 1250
#define JT (NTILES / GG)       // 10 tiles per block, exact (even -> clean ping-pong)
#define RSUB 8                 // partial sub-rows per (b,k,g)
#define PR 44                  // sub-row stride: 20 s1 + 20 s2 + 1 s0 + pad

// ws layout (floats)
#define WS_A 0                 // A coef [B*K] = 40 (padded to 64)
#define WS_R 64                // packed coef rows [B][F][10]: d[k] at +k, e[k] at +5+k

// ================= coefficient preparation =================
__global__ void prepare_kernel(const float* __restrict__ means, const float* __restrict__ var,
                               const float* __restrict__ pi, float* __restrict__ ws) {
    int t = threadIdx.x;
    if (t < BB * KK) {
        int b = t / KK, k = t % KK;
        float sumlog = 0.f, summ2 = 0.f;
        for (int f = 0; f < FF; ++f) {
            float v = var[t * FF + f];
            float m = means[t * FF + f];
            float ic = 1.f / (v + 1e-6f);
            sumlog += logf(6.283185307179586f * v);
            summ2  += ic * m * m;
            float* R = ws + WS_R + (b * FF + f) * 10;
            R[k]     = ic * m;      // d
            R[5 + k] = -0.5f * ic;  // e
        }
        (ws + WS_A)[t] = logf(pi[t]) - 0.5f * sumlog - 0.5f * summ2;
    }
}

// unpack 5 float4 -> 20 floats
__device__ __forceinline__ void unpack20(const float4* x4, float* xv) {
#pragma unroll
    for (int i = 0; i < 5; ++i) {
        xv[i * 4 + 0] = x4[i].x; xv[i * 4 + 1] = x4[i].y;
        xv[i * 4 + 2] = x4[i].z; xv[i * 4 + 3] = x4[i].w;
    }
}

// compute z0..z4 for one point from coefs
__device__ __forceinline__ void zcalc(const float* xv, const float* cf,
                                      float A0, float A1, float A2, float A3, float A4,
                                      float* z) {
    float z0 = A0, z1 = A1, z2 = A2, z3 = A3, z4 = A4;
#pragma unroll
    for (int f = 0; f < FF; ++f) {
        const float* r = cf + f * 10;
        float x = xv[f];
        z0 = fmaf(x, fmaf(r[5], x, r[0]), z0);
        z1 = fmaf(x, fmaf(r[6], x, r[1]), z1);
        z2 = fmaf(x, fmaf(r[7], x, r[2]), z2);
        z3 = fmaf(x, fmaf(r[8], x, r[3]), z3);
        z4 = fmaf(x, fmaf(r[9], x, r[4]), z4);
    }
    z[0] = z0; z[1] = z1; z[2] = z2; z[3] = z3; z[4] = z4;
}

// ================= E-step accumulate: no LDS, no barriers, prefetched =================
template <int KLO, int NK>
__device__ __forceinline__ void tile_acc(const float4* __restrict__ x4, const float* cf,
                                         float A0, float A1, float A2, float A3, float A4,
                                         float* __restrict__ s0, float (*__restrict__ s1)[FF],
                                         float (*__restrict__ s2)[FF]) {
    float xv[FF];
    unpack20(x4, xv);
    float z[5];
    zcalc(xv, cf, A0, A1, A2, A3, A4, z);
    float mx = fmaxf(fmaxf(fmaxf(z[0], z[1]), fmaxf(z[2], z[3])), z[4]);
    float e0 = __expf(z[0] - mx), e1 = __expf(z[1] - mx), e2 = __expf(z[2] - mx),
          e3 = __expf(z[3] - mx), e4 = __expf(z[4] - mx);
    float inv = 1.f / (e0 + e1 + e2 + e3 + e4);
    float ev[5] = {e0, e1, e2, e3, e4};
#pragma unroll
    for (int q = 0; q < NK; ++q) {
        float p = ev[KLO + q] * inv;
        s0[q] += p;
#pragma unroll
        for (int f = 0; f < FF; ++f) {
            float px = p * xv[f];
            s1[q][f] += px;
            s2[q][f] = fmaf(px, xv[f], s2[q][f]);
        }
    }
}

template <int KLO, int NK>
__device__ __forceinline__ void estep_acc_wave(const float* __restrict__ dbase,
                                               const float* __restrict__ cfbase,
                                               const float* __restrict__ Ab,
                                               int b, int g, int lane,
                                               float* __restrict__ partials) {
    const float A0 = Ab[0], A1 = Ab[1], A2 = Ab[2], A3 = Ab[3], A4 = Ab[4];
    float s0[NK], s1[NK][FF], s2[NK][FF];
#pragma unroll
    for (int q = 0; q < NK; ++q) {
        s0[q] = 0.f;
#pragma unroll
        for (int f = 0; f < FF; ++f) { s1[q][f] = 0.f; s2[q][f] = 0.f; }
    }

    float4 xa[5], xb[5];
    {
        const float4* tp = (const float4*)(dbase + (size_t)g * TILE * FF);
#pragma unroll
        for (int i = 0; i < 5; ++i) xa[i] = tp[lane * 5 + i];
    }

    for (int j = 0; j < JT; j += 2) {
        // non-volatile LICM blocker: coef loads stay per-iteration, scheduler stays free
        const float* cf = cfbase;
        asm("" : "+s"(cf) : "s"(j));
        {   // prefetch tile j+1 (JT even -> always valid)
            const float4* tp = (const float4*)(dbase + (size_t)(g + (j + 1) * GG) * TILE * FF);
#pragma unroll
            for (int i = 0; i < 5; ++i) xb[i] = tp[lane * 5 + i];
        }
        tile_acc<KLO, NK>(xa, cf, A0, A1, A2, A3, A4, s0, s1, s2);

        const float* cf2 = cfbase;
        int j1 = j + 1;
        asm("" : "+s"(cf2) : "s"(j1));
        if (j + 2 < JT) {   // prefetch tile j+2
            const float4* tp = (const float4*)(dbase + (size_t)(g + (j + 2) * GG) * TILE * FF);
#pragma unroll
            for (int i = 0; i < 5; ++i) xa[i] = tp[lane * 5 + i];
        }
        tile_acc<KLO, NK>(xb, cf2, A0, A1, A2, A3, A4, s0, s1, s2);
    }

    // 3-step shuffle reduce -> lanes 0..7 hold 8-way partial sums
#pragma unroll
    for (int off = 32; off >= 8; off >>= 1) {
#pragma unroll
        for (int q = 0; q < NK; ++q) {
            s0[q] += __shfl_down(s0[q], off);
#pragma unroll
            for (int f = 0; f < FF; ++f) {
                s1[q][f] += __shfl_down(s1[q][f], off);
                s2[q][f] += __shfl_down(s2[q][f], off);
            }
        }
    }
    if (lane < RSUB) {
#pragma unroll
        for (int q = 0; q < NK; ++q) {
            float* row = partials + (((size_t)(b * KK + KLO + q) * GG + g) * RSUB + lane) * PR;
#pragma unroll
            for (int f = 0; f < FF; ++f) { row[f] = s1[q][f]; row[FF + f] = s2[q][f]; }
            row[2 * FF] = s0[q];
        }
    }
}

__global__ __launch_bounds__(128, 2) void estep_acc_kernel(const float* __restrict__ data,
                                                           const float* __restrict__ ws,
                                                           float* __restrict__ partials) {
    const int b    = blockIdx.x & 7;    // batch <-> XCD pinning (3.2 MB fits 4 MB L2)
    const int g    = blockIdx.x >> 3;   // 0..124
    const int wv   = threadIdx.x >> 6;
    const int lane = threadIdx.x & 63;
    const float* cfbase = ws + WS_R + b * FF * 10;
    const float* Ab     = ws + WS_A + b * KK;
    const float* dbase  = data + (size_t)b * NPTS * FF;
    if (wv == 0) estep_acc_wave<0, 2>(dbase, cfbase, Ab, b, g, lane, partials);
    else         estep_acc_wave<2, 3>(dbase, cfbase, Ab, b, g, lane, partials);
}

// ================= final E-step: write ll & post =================
__global__ __launch_bounds__(128) void estep_write_kernel(const float* __restrict__ data,
                                                          const float* __restrict__ ws,
                                                          float* __restrict__ out_ll,
                                                          float* __restrict__ out_post) {
    const int b    = blockIdx.x & 7;
    const int g    = blockIdx.x >> 3;
    const int wv   = threadIdx.x >> 6;
    const int lane = threadIdx.x & 63;
    const float* cfbase = ws + WS_R + b * FF * 10;
    const float* Ab     = ws + WS_A + b * KK;
    const float* dbase  = data + (size_t)b * NPTS * FF;
    const float A0 = Ab[0], A1 = Ab[1], A2 = Ab[2], A3 = Ab[3], A4 = Ab[4];

    float4 xa[5], xb[5];
    {
        const float4* tp = (const float4*)(dbase + (size_t)g * TILE * FF);
#pragma unroll
        for (int i = 0; i < 5; ++i) xa[i] = tp[lane * 5 + i];
    }

    for (int j = 0; j < JT; j += 2) {
        const float* cf = cfbase;
        asm("" : "+s"(cf) : "s"(j));
        {
            const float4* tp = (const float4*)(dbase + (size_t)(g + (j + 1) * GG) * TILE * FF);
#pragma unroll
            for (int i = 0; i < 5; ++i) xb[i] = tp[lane * 5 + i];
        }
        // process tile j
        for (int half = 0; half < 2; ++half) {
            const float4* xc = (half == 0) ? xa : xb;
            const float* cfc = cf;
            if (half == 1) {
                int j1 = j + 1;
                cfc = cfbase;
                asm("" : "+s"(cfc) : "s"(j1));
                if (j + 2 < JT) {
                    const float4* tp =
                        (const float4*)(dbase + (size_t)(g + (j + 2) * GG) * TILE * FF);
#pragma unroll
                    for (int i = 0; i < 5; ++i) xa[i] = tp[lane * 5 + i];
                }
            }
            float xv[FF];
            unpack20(xc, xv);
            float z[5];
            zcalc(xv, cfc, A0, A1, A2, A3, A4, z);
            float mx = fmaxf(fmaxf(fmaxf(z[0], z[1]), fmaxf(z[2], z[3])), z[4]);
            float e0 = __expf(z[0] - mx), e1 = __expf(z[1] - mx), e2 = __expf(z[2] - mx),
                  e3 = __expf(z[3] - mx), e4 = __expf(z[4] - mx);
            float inv = 1.f / (e0 + e1 + e2 + e3 + e4);

            const int tile = g + (j + half) * GG;
            size_t o = ((size_t)b * NPTS + (size_t)tile * TILE + lane) * KK;
            if (wv == 0) {
                out_ll[o + 0] = z[0]; out_ll[o + 1] = z[1]; out_ll[o + 2] = z[2];
                out_ll[o + 3] = z[3]; out_ll[o + 4] = z[4];
            } else {
                out_post[o + 0] = e0 * inv; out_post[o + 1] = e1 * inv;
                out_post[o + 2] = e2 * inv; out_post[o + 3] = e3 * inv;
                out_post[o + 4] = e4 * inv;
            }
        }
    }
}

// ================= reduce partials + M-step + next coefs =================
__global__ __launch_bounds__(320) void update_kernel(const float* __restrict__ partials,
                                                     float* __restrict__ ws,
                                                     float* __restrict__ om,
                                                     float* __restrict__ ov,
                                                     float* __restrict__ op,
                                                     int write_params) {
    __shared__ float s0s[KK];
    const int b    = blockIdx.x;
    const int tid  = threadIdx.x;
    const int w    = tid >> 6;
    const int lane = tid & 63;
    const int bk   = b * KK + w;

    float a0 = 0.f, a1 = 0.f, a2 = 0.f, a3 = 0.f;
    if (lane < 2 * FF + 1) {
        const float* base = partials + (size_t)bk * GG * RSUB * PR + lane;
        for (int r = 0; r < GG * RSUB; r += 4) {   // 1000 rows, divisible by 4
            a0 += base[(size_t)(r + 0) * PR];
            a1 += base[(size_t)(r + 1) * PR];
            a2 += base[(size_t)(r + 2) * PR];
            a3 += base[(size_t)(r + 3) * PR];
        }
    }
    float sv = (a0 + a1) + (a2 + a3);

    float s0  = __shfl(sv, 2 * FF);
    float den = s0 + 1e-7f;
    float m   = sv / den;                      // lanes 0..19: mean[f]
    float s2f = __shfl(sv, FF + (lane % FF));  // S2[f] for lane f
    float var = (s2f - 2.f * m * sv + m * m * s0) / den + 1e-6f;

    if (write_params && lane < FF) {
        om[bk * FF + lane] = m;
        ov[bk * FF + lane] = var;
    }

    if (lane == 0) s0s[w] = s0;
    __syncthreads();
    float tot = s0s[0] + s0s[1] + s0s[2] + s0s[3] + s0s[4];
    float pr  = (s0 / (float)NPTS) / fmaxf(tot / (float)NPTS, 1e-12f);
    if (write_params && lane == 0) op[bk] = pr;

    // next-iteration coefs in-register
    float ic = 1.f / (var + 1e-6f);
    if (lane < FF) {
        float* R = ws + WS_R + (b * FF + lane) * 10;
        R[w]     = ic * m;
        R[5 + w] = -0.5f * ic;
    }
    float t1 = (lane < FF) ? logf(6.283185307179586f * var) : 0.f;
    float t2 = (lane < FF) ? ic * m * m : 0.f;
#pragma unroll
    for (int off = 1; off < 64; off <<= 1) {
        t1 += __shfl_xor(t1, off);
        t2 += __shfl_xor(t2, off);
    }
    if (lane == 0)
        (ws + WS_A)[bk] = logf(pr) - 0.5f * t1 - 0.5f * t2;
}

extern "C" void kernel_launch(void* const* d_in, const int* in_sizes, int n_in,
                              void* d_out, int out_size, void* d_ws, size_t ws_size,
                              hipStream_t stream) {
    const float* data     = (const float*)d_in[0];
    const float* in_means = (const float*)d_in[1];
    const float* in_var   = (const float*)d_in[2];
    const float* in_pi    = (const float*)d_in[3];
    float* ws  = (float*)d_ws;
    float* out = (float*)d_out;

    float* out_ll   = out;
    float* out_post = out + (size_t)BB * NPTS * KK;
    float* om       = out + 2 * (size_t)BB * NPTS * KK;
    float* ov       = om + BB * KK * FF;
    float* op       = ov + BB * KK * FF;

    // partials (8*5*125*8*44*4 = 7.04 MB) live in the ll output region (12.8 MB);
    // the final E-step fully overwrites it.
    float* partials = out_ll;

    prepare_kernel<<<1, 64, 0, stream>>>(in_means, in_var, in_pi, ws);

    for (int it = 0; it < 5; ++it) {
        estep_acc_kernel<<<BB * GG, 128, 0, stream>>>(data, ws, partials);
        update_kernel<<<BB, 320, 0, stream>>>(partials, ws, om, ov, op,
                                              (it == 4) ? 1 : 0);
    }
    estep_write_kernel<<<BB * GG, 128, 0, stream>>>(data, ws, out_ll, out_post);
}

// Round 7
// 437.020 us; speedup vs baseline: 2.1874x; 2.1874x over previous
//
#include <hip/hip_runtime.h>
#include <math.h>

#define BB 8
#define NPTS 80000
#define KK 5
#define FF 20
#define GG 125                 // blocks per batch -> 1000 blocks, 10 tiles each
#define TILE 64
#define NTILES (NPTS / TILE)   // 1250
#define JT (NTILES / GG)       // 10 tiles per block, exact (even -> clean ping-pong)
#define RSUB 8                 // partial sub-rows per (b,k,g)
#define PR 44                  // sub-row stride: 20 s1 + 20 s2 + 1 s0 + pad

// ws layout (floats)
#define WS_A 0                 // A coef [B*K] = 40 (padded to 64)
#define WS_R 64                // packed coef rows [B][F][10]: d[k] at +k, e[k] at +5+k

// ================= coefficient preparation =================
__global__ void prepare_kernel(const float* __restrict__ means, const float* __restrict__ var,
                               const float* __restrict__ pi, float* __restrict__ ws) {
    int t = threadIdx.x;
    if (t < BB * KK) {
        int b = t / KK, k = t % KK;
        float sumlog = 0.f, summ2 = 0.f;
        for (int f = 0; f < FF; ++f) {
            float v = var[t * FF + f];
            float m = means[t * FF + f];
            float ic = 1.f / (v + 1e-6f);
            sumlog += logf(6.283185307179586f * v);
            summ2  += ic * m * m;
            float* R = ws + WS_R + (b * FF + f) * 10;
            R[k]     = ic * m;      // d
            R[5 + k] = -0.5f * ic;  // e
        }
        (ws + WS_A)[t] = logf(pi[t]) - 0.5f * sumlog - 0.5f * summ2;
    }
}

// unpack 5 float4 -> 20 floats
__device__ __forceinline__ void unpack20(const float4* x4, float* xv) {
#pragma unroll
    for (int i = 0; i < 5; ++i) {
        xv[i * 4 + 0] = x4[i].x; xv[i * 4 + 1] = x4[i].y;
        xv[i * 4 + 2] = x4[i].z; xv[i * 4 + 3] = x4[i].w;
    }
}

// compute z0..z4 for one point from coefs
__device__ __forceinline__ void zcalc(const float* xv, const float* cf,
                                      float A0, float A1, float A2, float A3, float A4,
                                      float* z) {
    float z0 = A0, z1 = A1, z2 = A2, z3 = A3, z4 = A4;
#pragma unroll
    for (int f = 0; f < FF; ++f) {
        const float* r = cf + f * 10;
        float x = xv[f];
        z0 = fmaf(x, fmaf(r[5], x, r[0]), z0);
        z1 = fmaf(x, fmaf(r[6], x, r[1]), z1);
        z2 = fmaf(x, fmaf(r[7], x, r[2]), z2);
        z3 = fmaf(x, fmaf(r[8], x, r[3]), z3);
        z4 = fmaf(x, fmaf(r[9], x, r[4]), z4);
    }
    z[0] = z0; z[1] = z1; z[2] = z2; z[3] = z3; z[4] = z4;
}

// ================= E-step accumulate: no LDS, no barriers, prefetched =================
template <int KLO, int NK>
__device__ __forceinline__ void tile_acc(const float4* __restrict__ x4, const float* cf,
                                         float A0, float A1, float A2, float A3, float A4,
                                         float* __restrict__ s0, float (*__restrict__ s1)[FF],
                                         float (*__restrict__ s2)[FF]) {
    float xv[FF];
    unpack20(x4, xv);
    float z[5];
    zcalc(xv, cf, A0, A1, A2, A3, A4, z);
    float mx = fmaxf(fmaxf(fmaxf(z[0], z[1]), fmaxf(z[2], z[3])), z[4]);
    float e0 = __expf(z[0] - mx), e1 = __expf(z[1] - mx), e2 = __expf(z[2] - mx),
          e3 = __expf(z[3] - mx), e4 = __expf(z[4] - mx);
    float inv = 1.f / (e0 + e1 + e2 + e3 + e4);
    float ev[5] = {e0, e1, e2, e3, e4};
#pragma unroll
    for (int q = 0; q < NK; ++q) {
        float p = ev[KLO + q] * inv;
        s0[q] += p;
#pragma unroll
        for (int f = 0; f < FF; ++f) {
            float px = p * xv[f];
            s1[q][f] += px;
            s2[q][f] = fmaf(px, xv[f], s2[q][f]);
        }
    }
}

template <int KLO, int NK>
__device__ __forceinline__ void estep_acc_wave(const float* __restrict__ dbase,
                                               const float* __restrict__ cfbase,
                                               const float* __restrict__ Ab,
                                               int b, int g, int lane,
                                               float* __restrict__ partials) {
    const float A0 = Ab[0], A1 = Ab[1], A2 = Ab[2], A3 = Ab[3], A4 = Ab[4];
    float s0[NK], s1[NK][FF], s2[NK][FF];
#pragma unroll
    for (int q = 0; q < NK; ++q) {
        s0[q] = 0.f;
#pragma unroll
        for (int f = 0; f < FF; ++f) { s1[q][f] = 0.f; s2[q][f] = 0.f; }
    }

    float4 xa[5], xb[5];
    {
        const float4* tp = (const float4*)(dbase + (size_t)g * TILE * FF);
#pragma unroll
        for (int i = 0; i < 5; ++i) xa[i] = tp[lane * 5 + i];
    }

    for (int j = 0; j < JT; j += 2) {
        // non-volatile LICM blocker: coef loads stay per-iteration, scheduler stays free
        const float* cf = cfbase;
        asm("" : "+s"(cf) : "s"(j));
        {   // prefetch tile j+1 (JT even -> always valid)
            const float4* tp = (const float4*)(dbase + (size_t)(g + (j + 1) * GG) * TILE * FF);
#pragma unroll
            for (int i = 0; i < 5; ++i) xb[i] = tp[lane * 5 + i];
        }
        tile_acc<KLO, NK>(xa, cf, A0, A1, A2, A3, A4, s0, s1, s2);

        const float* cf2 = cfbase;
        int j1 = j + 1;
        asm("" : "+s"(cf2) : "s"(j1));
        if (j + 2 < JT) {   // prefetch tile j+2
            const float4* tp = (const float4*)(dbase + (size_t)(g + (j + 2) * GG) * TILE * FF);
#pragma unroll
            for (int i = 0; i < 5; ++i) xa[i] = tp[lane * 5 + i];
        }
        tile_acc<KLO, NK>(xb, cf2, A0, A1, A2, A3, A4, s0, s1, s2);
    }

    // 3-step shuffle reduce -> lanes 0..7 hold 8-way partial sums
#pragma unroll
    for (int off = 32; off >= 8; off >>= 1) {
#pragma unroll
        for (int q = 0; q < NK; ++q) {
            s0[q] += __shfl_down(s0[q], off);
#pragma unroll
            for (int f = 0; f < FF; ++f) {
                s1[q][f] += __shfl_down(s1[q][f], off);
                s2[q][f] += __shfl_down(s2[q][f], off);
            }
        }
    }
    if (lane < RSUB) {
#pragma unroll
        for (int q = 0; q < NK; ++q) {
            float* row = partials + (((size_t)(b * KK + KLO + q) * GG + g) * RSUB + lane) * PR;
#pragma unroll
            for (int f = 0; f < FF; ++f) { row[f] = s1[q][f]; row[FF + f] = s2[q][f]; }
            row[2 * FF] = s0[q];
        }
    }
}

// plain __launch_bounds__(128): R6's (128,2) let the compiler target 4 waves/SIMD,
// cap VGPR at 128, and spill the accumulators (WRITE_SIZE 6.9->309 MB). Do not
// re-add a min-waves hint here.
__global__ __launch_bounds__(128) void estep_acc_kernel(const float* __restrict__ data,
                                                        const float* __restrict__ ws,
                                                        float* __restrict__ partials) {
    const int b    = blockIdx.x & 7;    // batch <-> XCD pinning (3.2 MB fits 4 MB L2)
    const int g    = blockIdx.x >> 3;   // 0..124
    const int wv   = threadIdx.x >> 6;
    const int lane = threadIdx.x & 63;
    const float* cfbase = ws + WS_R + b * FF * 10;
    const float* Ab     = ws + WS_A + b * KK;
    const float* dbase  = data + (size_t)b * NPTS * FF;
    if (wv == 0) estep_acc_wave<0, 2>(dbase, cfbase, Ab, b, g, lane, partials);
    else         estep_acc_wave<2, 3>(dbase, cfbase, Ab, b, g, lane, partials);
}

// ================= final E-step: write ll & post =================
__global__ __launch_bounds__(128) void estep_write_kernel(const float* __restrict__ data,
                                                          const float* __restrict__ ws,
                                                          float* __restrict__ out_ll,
                                                          float* __restrict__ out_post) {
    const int b    = blockIdx.x & 7;
    const int g    = blockIdx.x >> 3;
    const int wv   = threadIdx.x >> 6;
    const int lane = threadIdx.x & 63;
    const float* cfbase = ws + WS_R + b * FF * 10;
    const float* Ab     = ws + WS_A + b * KK;
    const float* dbase  = data + (size_t)b * NPTS * FF;
    const float A0 = Ab[0], A1 = Ab[1], A2 = Ab[2], A3 = Ab[3], A4 = Ab[4];

    float4 xa[5], xb[5];
    {
        const float4* tp = (const float4*)(dbase + (size_t)g * TILE * FF);
#pragma unroll
        for (int i = 0; i < 5; ++i) xa[i] = tp[lane * 5 + i];
    }

    for (int j = 0; j < JT; j += 2) {
        const float* cf = cfbase;
        asm("" : "+s"(cf) : "s"(j));
        {
            const float4* tp = (const float4*)(dbase + (size_t)(g + (j + 1) * GG) * TILE * FF);
#pragma unroll
            for (int i = 0; i < 5; ++i) xb[i] = tp[lane * 5 + i];
        }
        for (int half = 0; half < 2; ++half) {
            const float4* xc = (half == 0) ? xa : xb;
            const float* cfc = cf;
            if (half == 1) {
                int j1 = j + 1;
                cfc = cfbase;
                asm("" : "+s"(cfc) : "s"(j1));
                if (j + 2 < JT) {
                    const float4* tp =
                        (const float4*)(dbase + (size_t)(g + (j + 2) * GG) * TILE * FF);
#pragma unroll
                    for (int i = 0; i < 5; ++i) xa[i] = tp[lane * 5 + i];
                }
            }
            float xv[FF];
            unpack20(xc, xv);
            float z[5];
            zcalc(xv, cfc, A0, A1, A2, A3, A4, z);
            float mx = fmaxf(fmaxf(fmaxf(z[0], z[1]), fmaxf(z[2], z[3])), z[4]);
            float e0 = __expf(z[0] - mx), e1 = __expf(z[1] - mx), e2 = __expf(z[2] - mx),
                  e3 = __expf(z[3] - mx), e4 = __expf(z[4] - mx);
            float inv = 1.f / (e0 + e1 + e2 + e3 + e4);

            const int tile = g + (j + half) * GG;
            size_t o = ((size_t)b * NPTS + (size_t)tile * TILE + lane) * KK;
            if (wv == 0) {
                out_ll[o + 0] = z[0]; out_ll[o + 1] = z[1]; out_ll[o + 2] = z[2];
                out_ll[o + 3] = z[3]; out_ll[o + 4] = z[4];
            } else {
                out_post[o + 0] = e0 * inv; out_post[o + 1] = e1 * inv;
                out_post[o + 2] = e2 * inv; out_post[o + 3] = e3 * inv;
                out_post[o + 4] = e4 * inv;
            }
        }
    }
}

// ================= reduce partials + M-step + next coefs =================
__global__ __launch_bounds__(320) void update_kernel(const float* __restrict__ partials,
                                                     float* __restrict__ ws,
                                                     float* __restrict__ om,
                                                     float* __restrict__ ov,
                                                     float* __restrict__ op,
                                                     int write_params) {
    __shared__ float s0s[KK];
    const int b    = blockIdx.x;
    const int tid  = threadIdx.x;
    const int w    = tid >> 6;
    const int lane = tid & 63;
    const int bk   = b * KK + w;

    float a0 = 0.f, a1 = 0.f, a2 = 0.f, a3 = 0.f;
    if (lane < 2 * FF + 1) {
        const float* base = partials + (size_t)bk * GG * RSUB * PR + lane;
        for (int r = 0; r < GG * RSUB; r += 4) {   // 1000 rows, divisible by 4
            a0 += base[(size_t)(r + 0) * PR];
            a1 += base[(size_t)(r + 1) * PR];
            a2 += base[(size_t)(r + 2) * PR];
            a3 += base[(size_t)(r + 3) * PR];
        }
    }
    float sv = (a0 + a1) + (a2 + a3);

    float s0  = __shfl(sv, 2 * FF);
    float den = s0 + 1e-7f;
    float m   = sv / den;                      // lanes 0..19: mean[f]
    float s2f = __shfl(sv, FF + (lane % FF));  // S2[f] for lane f
    float var = (s2f - 2.f * m * sv + m * m * s0) / den + 1e-6f;

    if (write_params && lane < FF) {
        om[bk * FF + lane] = m;
        ov[bk * FF + lane] = var;
    }

    if (lane == 0) s0s[w] = s0;
    __syncthreads();
    float tot = s0s[0] + s0s[1] + s0s[2] + s0s[3] + s0s[4];
    float pr  = (s0 / (float)NPTS) / fmaxf(tot / (float)NPTS, 1e-12f);
    if (write_params && lane == 0) op[bk] = pr;

    // next-iteration coefs in-register
    float ic = 1.f / (var + 1e-6f);
    if (lane < FF) {
        float* R = ws + WS_R + (b * FF + lane) * 10;
        R[w]     = ic * m;
        R[5 + w] = -0.5f * ic;
    }
    float t1 = (lane < FF) ? logf(6.283185307179586f * var) : 0.f;
    float t2 = (lane < FF) ? ic * m * m : 0.f;
#pragma unroll
    for (int off = 1; off < 64; off <<= 1) {
        t1 += __shfl_xor(t1, off);
        t2 += __shfl_xor(t2, off);
    }
    if (lane == 0)
        (ws + WS_A)[bk] = logf(pr) - 0.5f * t1 - 0.5f * t2;
}

extern "C" void kernel_launch(void* const* d_in, const int* in_sizes, int n_in,
                              void* d_out, int out_size, void* d_ws, size_t ws_size,
                              hipStream_t stream) {
    const float* data     = (const float*)d_in[0];
    const float* in_means = (const float*)d_in[1];
    const float* in_var   = (const float*)d_in[2];
    const float* in_pi    = (const float*)d_in[3];
    float* ws  = (float*)d_ws;
    float* out = (float*)d_out;

    float* out_ll   = out;
    float* out_post = out + (size_t)BB * NPTS * KK;
    float* om       = out + 2 * (size_t)BB * NPTS * KK;
    float* ov       = om + BB * KK * FF;
    float* op       = ov + BB * KK * FF;

    // partials (8*5*125*8*44*4 = 7.04 MB) live in the ll output region (12.8 MB);
    // the final E-step fully overwrites it.
    float* partials = out_ll;

    prepare_kernel<<<1, 64, 0, stream>>>(in_means, in_var, in_pi, ws);

    for (int it = 0; it < 5; ++it) {
        estep_acc_kernel<<<BB * GG, 128, 0, stream>>>(data, ws, partials);
        update_kernel<<<BB, 320, 0, stream>>>(partials, ws, om, ov, op,
                                              (it == 4) ? 1 : 0);
    }
    estep_write_kernel<<<BB * GG, 128, 0, stream>>>(data, ws, out_ll, out_post);
}

// Round 8
// 313.657 us; speedup vs baseline: 3.0478x; 1.3933x over previous
//
#include <hip/hip_runtime.h>
#include <math.h>

#define BB 8
#define NPTS 80000
#define KK 5
#define FF 20
#define GG 125                 // blocks per batch -> 1000 blocks, 10 tiles each
#define TILE 64
#define NTILES (NPTS / TILE)   // 1250
#define JT (NTILES / GG)       // 10 tiles per block, exact (even -> clean ping-pong)
#define RSUB 8                 // partial sub-rows per (b,k,g)
#define PR 44                  // sub-row stride: 20 s1 + 20 s2 + 1 s0 + pad

// ws layout (floats): A[40] (pad to 64), D[b*K+k][f] = 800, E same
#define WS_A 0
#define WS_D 64
#define WS_E 864

// ================= coefficient preparation =================
__global__ void prepare_kernel(const float* __restrict__ means, const float* __restrict__ var,
                               const float* __restrict__ pi, float* __restrict__ ws) {
    int t = threadIdx.x;
    if (t < BB * KK) {
        float sumlog = 0.f, summ2 = 0.f;
        for (int f = 0; f < FF; ++f) {
            float v = var[t * FF + f];
            float m = means[t * FF + f];
            float ic = 1.f / (v + 1e-6f);
            sumlog += logf(6.283185307179586f * v);
            summ2  += ic * m * m;
            (ws + WS_D)[t * FF + f] = ic * m;
            (ws + WS_E)[t * FF + f] = -0.5f * ic;
        }
        (ws + WS_A)[t] = logf(pi[t]) - 0.5f * sumlog - 0.5f * summ2;
    }
}

__device__ __forceinline__ void unpack20(const float4* x4, float* xv) {
#pragma unroll
    for (int i = 0; i < 5; ++i) {
        xv[i * 4 + 0] = x4[i].x; xv[i * 4 + 1] = x4[i].y;
        xv[i * 4 + 2] = x4[i].z; xv[i * 4 + 3] = x4[i].w;
    }
}

// ---- one 64-point tile: z (own clusters) -> LDS exchange -> softmax -> acc/write ----
template <int ZLO, int ZN, int ALO, int AN, bool WRITE_OUT>
__device__ __forceinline__ void tile_proc(const float4* __restrict__ x4, int j, int b, int g,
                                          int lane,
                                          const float (&dk)[ZN][FF], const float (&ek)[ZN][FF],
                                          const float (&Az)[ZN],
                                          float (*__restrict__ lls)[KK][TILE],
                                          float* __restrict__ s0,
                                          float (*__restrict__ s1)[FF],
                                          float (*__restrict__ s2)[FF],
                                          float* __restrict__ out_ll,
                                          float* __restrict__ out_post) {
    float xv[FF];
    unpack20(x4, xv);
    const int p = j & 1;

    float zq[ZN];
#pragma unroll
    for (int q = 0; q < ZN; ++q) {
        float z = Az[q];
#pragma unroll
        for (int f = 0; f < FF; ++f)
            z = fmaf(xv[f], fmaf(ek[q][f], xv[f], dk[q][f]), z);
        zq[q] = z;
        lls[p][ZLO + q][lane] = z;
    }
    __syncthreads();   // both waves' z written; double-buffer makes 1 barrier/tile safe

    float z[KK];
#pragma unroll
    for (int k = 0; k < KK; ++k)
        z[k] = (k >= ZLO && k < ZLO + ZN) ? zq[k - ZLO] : lls[p][k][lane];

    float mx = fmaxf(fmaxf(fmaxf(z[0], z[1]), fmaxf(z[2], z[3])), z[4]);
    float e[KK];
#pragma unroll
    for (int k = 0; k < KK; ++k) e[k] = __expf(z[k] - mx);
    float inv = 1.f / (e[0] + e[1] + e[2] + e[3] + e[4]);

    if (WRITE_OUT) {
        size_t o = ((size_t)b * NPTS + (size_t)(g + j * GG) * TILE + lane) * KK;
        if (ZLO == 0) {          // wave0 writes ll
#pragma unroll
            for (int k = 0; k < KK; ++k) out_ll[o + k] = z[k];
        } else {                 // wave1 writes post
#pragma unroll
            for (int k = 0; k < KK; ++k) out_post[o + k] = e[k] * inv;
        }
    } else {
#pragma unroll
        for (int q = 0; q < AN; ++q) {
            float pp = e[ALO + q] * inv;
            s0[q] += pp;
#pragma unroll
            for (int f = 0; f < FF; ++f) {
                float px = pp * xv[f];
                s1[q][f] += px;
                s2[q][f] = fmaf(px, xv[f], s2[q][f]);
            }
        }
    }
}

template <int ZLO, int ZN, int ALO, int AN, bool WRITE_OUT>
__device__ __forceinline__ void estep_wave(const float* __restrict__ dbase,
                                           const float* __restrict__ ws,
                                           int b, int g, int lane,
                                           float (*__restrict__ lls)[KK][TILE],
                                           float* __restrict__ partials,
                                           float* __restrict__ out_ll,
                                           float* __restrict__ out_post) {
    // coefs for this wave's z-clusters: loaded ONCE into SGPRs (wave-uniform)
    float dk[ZN][FF], ek[ZN][FF], Az[ZN];
#pragma unroll
    for (int q = 0; q < ZN; ++q) {
        const int bk = b * KK + ZLO + q;
        Az[q] = (ws + WS_A)[bk];
#pragma unroll
        for (int f = 0; f < FF; ++f) {
            dk[q][f] = (ws + WS_D)[bk * FF + f];
            ek[q][f] = (ws + WS_E)[bk * FF + f];
        }
    }

    float s0[AN], s1[AN][FF], s2[AN][FF];
    if (!WRITE_OUT) {
#pragma unroll
        for (int q = 0; q < AN; ++q) {
            s0[q] = 0.f;
#pragma unroll
            for (int f = 0; f < FF; ++f) { s1[q][f] = 0.f; s2[q][f] = 0.f; }
        }
    }

    float4 xa[5], xb[5];
    {
        const float4* tp = (const float4*)(dbase + (size_t)g * TILE * FF);
#pragma unroll
        for (int i = 0; i < 5; ++i) xa[i] = tp[lane * 5 + i];
    }

    for (int j = 0; j < JT; j += 2) {
        {   // prefetch tile j+1 (JT even -> always valid)
            const float4* tp = (const float4*)(dbase + (size_t)(g + (j + 1) * GG) * TILE * FF);
#pragma unroll
            for (int i = 0; i < 5; ++i) xb[i] = tp[lane * 5 + i];
        }
        tile_proc<ZLO, ZN, ALO, AN, WRITE_OUT>(xa, j, b, g, lane, dk, ek, Az, lls,
                                               s0, s1, s2, out_ll, out_post);
        if (j + 2 < JT) {   // prefetch tile j+2
            const float4* tp = (const float4*)(dbase + (size_t)(g + (j + 2) * GG) * TILE * FF);
#pragma unroll
            for (int i = 0; i < 5; ++i) xa[i] = tp[lane * 5 + i];
        }
        tile_proc<ZLO, ZN, ALO, AN, WRITE_OUT>(xb, j + 1, b, g, lane, dk, ek, Az, lls,
                                               s0, s1, s2, out_ll, out_post);
    }

    if (!WRITE_OUT) {
        // 3-step shuffle reduce -> lanes 0..7 hold 8-way partial sums
#pragma unroll
        for (int off = 32; off >= 8; off >>= 1) {
#pragma unroll
            for (int q = 0; q < AN; ++q) {
                s0[q] += __shfl_down(s0[q], off);
#pragma unroll
                for (int f = 0; f < FF; ++f) {
                    s1[q][f] += __shfl_down(s1[q][f], off);
                    s2[q][f] += __shfl_down(s2[q][f], off);
                }
            }
        }
        if (lane < RSUB) {
#pragma unroll
            for (int q = 0; q < AN; ++q) {
                float* row =
                    partials + (((size_t)(b * KK + ALO + q) * GG + g) * RSUB + lane) * PR;
#pragma unroll
                for (int f = 0; f < FF; ++f) { row[f] = s1[q][f]; row[FF + f] = s2[q][f]; }
                row[2 * FF] = s0[q];
            }
        }
    }
}

// plain __launch_bounds__(128): a min-waves hint here caused catastrophic spills (R6).
template <bool WRITE_OUT>
__global__ __launch_bounds__(128) void estep_kernel(const float* __restrict__ data,
                                                    const float* __restrict__ ws,
                                                    float* __restrict__ partials,
                                                    float* __restrict__ out_ll,
                                                    float* __restrict__ out_post) {
    __shared__ float lls[2][KK][TILE];   // double-buffered z-exchange (2560 B)
    const int b    = blockIdx.x & 7;
    const int g    = blockIdx.x >> 3;    // 0..124
    const int wv   = __builtin_amdgcn_readfirstlane(threadIdx.x >> 6);
    const int lane = threadIdx.x & 63;
    const float* dbase = data + (size_t)b * NPTS * FF;
    if (wv == 0)
        estep_wave<0, 3, 0, 2, WRITE_OUT>(dbase, ws, b, g, lane, lls, partials,
                                          out_ll, out_post);
    else
        estep_wave<3, 2, 2, 3, WRITE_OUT>(dbase, ws, b, g, lane, lls, partials,
                                          out_ll, out_post);
}

// ================= reduce partials + M-step + next coefs =================
__global__ __launch_bounds__(320) void update_kernel(const float* __restrict__ partials,
                                                     float* __restrict__ ws,
                                                     float* __restrict__ om,
                                                     float* __restrict__ ov,
                                                     float* __restrict__ op,
                                                     int write_params) {
    __shared__ float s0s[KK];
    const int b    = blockIdx.x;
    const int tid  = threadIdx.x;
    const int w    = tid >> 6;
    const int lane = tid & 63;
    const int bk   = b * KK + w;

    float a0 = 0.f, a1 = 0.f, a2 = 0.f, a3 = 0.f;
    if (lane < 2 * FF + 1) {
        const float* base = partials + (size_t)bk * GG * RSUB * PR + lane;
        for (int r = 0; r < GG * RSUB; r += 4) {   // 1000 rows
            a0 += base[(size_t)(r + 0) * PR];
            a1 += base[(size_t)(r + 1) * PR];
            a2 += base[(size_t)(r + 2) * PR];
            a3 += base[(size_t)(r + 3) * PR];
        }
    }
    float sv = (a0 + a1) + (a2 + a3);

    float s0  = __shfl(sv, 2 * FF);
    float den = s0 + 1e-7f;
    float m   = sv / den;                      // lanes 0..19: mean[f]
    float s2f = __shfl(sv, FF + (lane % FF));  // S2[f] for lane f
    float var = (s2f - 2.f * m * sv + m * m * s0) / den + 1e-6f;

    if (write_params && lane < FF) {
        om[bk * FF + lane] = m;
        ov[bk * FF + lane] = var;
    }

    if (lane == 0) s0s[w] = s0;
    __syncthreads();
    float tot = s0s[0] + s0s[1] + s0s[2] + s0s[3] + s0s[4];
    float pr  = (s0 / (float)NPTS) / fmaxf(tot / (float)NPTS, 1e-12f);
    if (write_params && lane == 0) op[bk] = pr;

    // next-iteration coefs
    float ic = 1.f / (var + 1e-6f);
    if (lane < FF) {
        (ws + WS_D)[bk * FF + lane] = ic * m;
        (ws + WS_E)[bk * FF + lane] = -0.5f * ic;
    }
    float t1 = (lane < FF) ? logf(6.283185307179586f * var) : 0.f;
    float t2 = (lane < FF) ? ic * m * m : 0.f;
#pragma unroll
    for (int off = 1; off < 64; off <<= 1) {
        t1 += __shfl_xor(t1, off);
        t2 += __shfl_xor(t2, off);
    }
    if (lane == 0)
        (ws + WS_A)[bk] = logf(pr) - 0.5f * t1 - 0.5f * t2;
}

extern "C" void kernel_launch(void* const* d_in, const int* in_sizes, int n_in,
                              void* d_out, int out_size, void* d_ws, size_t ws_size,
                              hipStream_t stream) {
    const float* data     = (const float*)d_in[0];
    const float* in_means = (const float*)d_in[1];
    const float* in_var   = (const float*)d_in[2];
    const float* in_pi    = (const float*)d_in[3];
    float* ws  = (float*)d_ws;
    float* out = (float*)d_out;

    float* out_ll   = out;
    float* out_post = out + (size_t)BB * NPTS * KK;
    float* om       = out + 2 * (size_t)BB * NPTS * KK;
    float* ov       = om + BB * KK * FF;
    float* op       = ov + BB * KK * FF;

    // partials (7.04 MB) live in the ll output region (12.8 MB);
    // the final E-step fully overwrites it.
    float* partials = out_ll;

    prepare_kernel<<<1, 64, 0, stream>>>(in_means, in_var, in_pi, ws);

    for (int it = 0; it < 5; ++it) {
        estep_kernel<false><<<BB * GG, 128, 0, stream>>>(data, ws, partials,
                                                         nullptr, nullptr);
        update_kernel<<<BB, 320, 0, stream>>>(partials, ws, om, ov, op,
                                              (it == 4) ? 1 : 0);
    }
    estep_kernel<true><<<BB * GG, 128, 0, stream>>>(data, ws, nullptr,
                                                    out_ll, out_post);
}